// Round 14
// baseline (622.125 us; speedup 1.0000x reference)
//
#include <hip/hip_runtime.h>
#include <hip/hip_fp16.h>
#include <cstdint>

#define T_STEPS 512
#define HDIM    256
#define ROWS    8
#define LN_EPS  1e-5f

typedef _Float16 half8   __attribute__((ext_vector_type(8)));
typedef _Float16 half4v  __attribute__((ext_vector_type(4)));
typedef __fp16   fp16x2  __attribute__((ext_vector_type(2)));   // cvt_pkrtz ret type
typedef float    float4v __attribute__((ext_vector_type(4)));
typedef float    float2v __attribute__((ext_vector_type(2)));
typedef int      int4v   __attribute__((ext_vector_type(4)));
typedef int      int2v   __attribute__((ext_vector_type(2)));

// R10: R8b (573us, best) + VOP3P packed-pair VALU in the tail. Budget model
// (fits 2686 cyc/step to ~1%): MFMA 1260 + VALU 510 + DS 700 + residue 200,
// nearly serial. MFMA/DS irreducible for this decomposition; R9 showed the
// tail-split overlap lever is spent. This round shrinks the VALU term by
// expressing the tail's elementwise chains as float2v so clang emits
// v_pk_fma_f32 / v_pk_mul_f32 / v_pk_add_f32 (2 f32 per issue).
// Numerics: per-element identical to R8b (same fma contractions; absmax
// 0.0039 verified there, 16x margin).
#if __has_builtin(__builtin_amdgcn_permlane32_swap)
#define HAS_PL32 1
#else
#define HAS_PL32 0
#endif
#if __has_builtin(__builtin_amdgcn_permlane16_swap)
#define HAS_PL16 1
#else
#define HAS_PL16 0
#endif

struct __align__(16) Smem {
  _Float16 Bp[2][4096];     // 16384 B packed B fragments (double-buffered)
  float    gb[10][268];     // 10720 B gb[v][n] = tanh(v*we+be)@W + bu + beta@W
  float    wg[260];         // 1040 B  gamma @ W (deferred-LN mu term)
  float    wb[260];         // 1040 B  beta @ W
  float    red[2][8][20];   // 1280 B  [buf][row][wv*2+{0:S,1:Sq}], 8 slots
  int      xi[8][516];      // 16512 B clamped x indices (+4 pad for quad reads)
};

__device__ __forceinline__ float tanh_fast(float x) {
  float e = __expf(2.0f * x);
  float r = __builtin_amdgcn_rcpf(e + 1.0f);
  return fmaf(-2.0f, r, 1.0f);
}
// lane l -> l^8 (rotate-by-8 within each 16-lane row == xor 8), pure VALU
__device__ __forceinline__ float dpp_ror8(float v) {
  return __int_as_float(__builtin_amdgcn_mov_dpp(__float_as_int(v), 0x128, 0xf, 0xf, true));
}
// lane l -> l^16 (within 32-lane half), LDS crossbar, conflict-free (verified R1/R4)
__device__ __forceinline__ float swz_xor16(float v) {
  return __int_as_float(__builtin_amdgcn_ds_swizzle(__float_as_int(v), 0x401F));
}
// v[l] + v[l^16] in every lane
__device__ __forceinline__ float sum_xor16(float v) {
#if HAS_PL16
  int2v r2 = __builtin_amdgcn_permlane16_swap(__float_as_int(v), __float_as_int(v), false, false);
  return __int_as_float(r2[0]) + __int_as_float(r2[1]);
#else
  return v + swz_xor16(v);
#endif
}
// v[l] + v[l^32] in every lane
__device__ __forceinline__ float sum_xor32(float v) {
#if HAS_PL32
  int2v r2 = __builtin_amdgcn_permlane32_swap(__float_as_int(v), __float_as_int(v), false, false);
  return __int_as_float(r2[0]) + __int_as_float(r2[1]);
#else
  return v + __shfl_xor(v, 32, 64);
#endif
}

__global__ __launch_bounds__(512, 1)
void rnn_scan_kernel(const float* __restrict__ x,
                     const float* __restrict__ we,  const float* __restrict__ be,
                     const float* __restrict__ Wu,  const float* __restrict__ bu,
                     const float* __restrict__ gma, const float* __restrict__ bta,
                     const float* __restrict__ Wo,  const float* __restrict__ bo,
                     float* __restrict__ out)
{
  __shared__ Smem sm;
  const int tid = threadIdx.x;
  const int wv  = tid >> 6;        // wave 0..7, owns n in [32*wv, 32*wv+32)
  const int l   = tid & 63;
  const int q   = l >> 4;
  const int m   = l & 15;
  const int sel = m >> 3;          // 0: finalize nt=0 (hi cols), 1: nt=1
  const int r   = m & 7;           // batch row within tile
  const int r0  = blockIdx.x * ROWS;

  // ---- init 0: x -> clamped int indices in LDS (the ONLY x reads) ----
  for (int i = tid; i < ROWS * T_STEPS; i += 512) {
    const int rr = i >> 9, c = i & (T_STEPS - 1);
    int xv = (int)x[(size_t)(r0 + rr) * T_STEPS + c];
    xv = xv < 0 ? 0 : (xv > 9 ? 9 : xv);
    sm.xi[rr][c] = xv;
  }
  if (tid < ROWS) {                // 4-entry zero pad for the quad prefetch
    sm.xi[tid][512] = 0; sm.xi[tid][513] = 0;
    sm.xi[tid][514] = 0; sm.xi[tid][515] = 0;
  }

  // ---- init 1: embed-tanh table in (to-be-zeroed) Bp space ----
  float* et = reinterpret_cast<float*>(&sm.Bp[0][0]);   // 10240 B < 16384 B
  if (tid < HDIM) {
    const float wek = we[tid], bek = be[tid];
    #pragma unroll
    for (int v = 0; v < 10; ++v)
      et[v*HDIM + tid] = tanh_fast(fmaf((float)v, wek, bek));
  }
  __syncthreads();

  // ---- init 2: gb = et@W + bu ; wg = gamma@W ; wb = beta@W ----
  {
    const int g = tid >> 8;        // 0: v=0..4 + wg, 1: v=5..9 + wb
    const int n = tid & 255;
    float acc[5] = {0,0,0,0,0};
    float accx = 0.0f;
    const int vb = g * 5;
    for (int k = 0; k < HDIM; ++k) {
      const float wk = Wu[(size_t)k*HDIM + n];
      #pragma unroll
      for (int v = 0; v < 5; ++v) acc[v] = fmaf(et[(vb+v)*HDIM + k], wk, acc[v]);
      const float xk = g ? bta[k] : gma[k];
      accx = fmaf(xk, wk, accx);
    }
    const float bun = bu[n];
    #pragma unroll
    for (int v = 0; v < 5; ++v) sm.gb[vb+v][n] = acc[v] + bun;
    if (g == 0) sm.wg[n] = accx; else sm.wb[n] = accx;
  }
  __syncthreads();

  // ---- init 3: fold beta@W into gb; zero Bp (both bufs) and red ----
  if (tid < HDIM) {
    const float wbn = sm.wb[tid];
    #pragma unroll
    for (int v = 0; v < 10; ++v) sm.gb[v][tid] += wbn;
  }
  {
    uint32_t* p = reinterpret_cast<uint32_t*>(&sm.Bp[0][0]);
    for (int i = tid; i < 4096; i += 512) p[i] = 0u;      // 16 KB = both bufs
  }
  if (tid < 320) (&sm.red[0][0][0])[tid] = 0.0f;

  // ---- persistent W fragments: full K, this wave's two 16-wide n-tiles ----
  half8 Whi[2][8], Wlo[2][8];
  #pragma unroll
  for (int nt = 0; nt < 2; ++nt) {
    const int n = wv*32 + nt*16 + m;
    #pragma unroll
    for (int kt = 0; kt < 8; ++kt) {
      const int k0 = kt*32 + q*8;
      half8 hi, lo;
      #pragma unroll
      for (int j = 0; j < 8; ++j) {
        float v = Wu[(size_t)(k0 + j)*HDIM + n];           // L2-hot across blocks
        _Float16 h = (_Float16)v;
        hi[j] = h;
        lo[j] = (_Float16)((v - (float)h) * 2048.0f);
      }
      Whi[nt][kt] = hi; Wlo[nt][kt] = lo;
    }
  }
  const int n_sel = wv*32 + sel*16 + q*4;    // this lane's 4 finalized columns
  const float4v gmr = *reinterpret_cast<const float4v*>(&gma[n_sel]);
  __syncthreads();                            // wg/gb/xi ready, buffers zeroed
  const float4v wgr = *reinterpret_cast<const float4v*>(&sm.wg[n_sel]);

  const float c1 = 4.8828125e-4f;             // 2^-11
  const float* gbp = &sm.gb[0][n_sel];
  float4v th4;                                // last tanh outputs (epilogue)

  // pair-split constants for the packed tail
  float2v wgr_a, wgr_b, gmr_a, gmr_b;
  wgr_a[0] = wgr[0]; wgr_a[1] = wgr[1]; wgr_b[0] = wgr[2]; wgr_b[1] = wgr[3];
  gmr_a[0] = gmr[0]; gmr_a[1] = gmr[1]; gmr_b[0] = gmr[2]; gmr_b[1] = gmr[3];

  // per-lane constant LDS offsets (halves)
  const int rdoff = l * 8;                                        // B read base
  const int woff  = wv*512 + (2*sel + (q>>1))*128 + r*8 + (q&1)*4; // hi write; lo at +64

  // x-index quad prefetch (one b128 per 4 steps) + gb bias row one step ahead
  int4v xQ = *reinterpret_cast<const int4v*>(&sm.xi[r][0]);
  float4v gbv_n = *reinterpret_cast<const float4v*>(gbp + xQ[0]*268);

  for (int k = 0; k < T_STEPS/4; ++k) {
    const int4v xQn = *reinterpret_cast<const int4v*>(&sm.xi[r][k*4 + 4]);
    #pragma unroll
    for (int e = 0; e < 4; ++e) {
      const int rb = e & 1, wb = rb ^ 1;

      // issue red chunk read NOW, consume in the stats block (latency hidden)
      const float4v pq = *reinterpret_cast<const float4v*>(&sm.red[rb][r][q*4]);

      const float4v gbv = gbv_n;                 // bias row for THIS step
      const int xv2 = (e < 3) ? xQ[e + 1] : xQn[0];   // compile-time select

      // hoist all B fragments into registers (static-indexed; rule #20 safe)
      const _Float16* pbB = &sm.Bp[rb][rdoff];
      half8 bfr[8];
      #pragma unroll
      for (int kt = 0; kt < 8; ++kt)
        bfr[kt] = *reinterpret_cast<const half8*>(pbB + kt*512);

      // ---- MFMA block A: tile0 chains (16 MFMAs) ----
      float4v d10, d11, d20, d21;
      d10 = 0.0f; d11 = 0.0f; d20 = 0.0f; d21 = 0.0f;
      __builtin_amdgcn_s_setprio(1);
      #pragma unroll
      for (int kt = 0; kt < 8; ++kt) {
        d10 = __builtin_amdgcn_mfma_f32_16x16x32_f16(Whi[0][kt], bfr[kt], d10, 0, 0, 0);
        d20 = __builtin_amdgcn_mfma_f32_16x16x32_f16(Wlo[0][kt], bfr[kt], d20, 0, 0, 0);
      }
      __builtin_amdgcn_s_setprio(0);

      // ---- stats block (independent VALU, anti-phases vs partner's MFMAs) ----
      gbv_n = *reinterpret_cast<const float4v*>(gbp + xv2*268);   // t+1 prefetch
      // packed pair-add: {S,Sq} = {pq0,pq1} + {pq2,pq3}
      float2v ssq;
      {
        float2v a, b;
        a[0] = pq[0]; a[1] = pq[1]; b[0] = pq[2]; b[1] = pq[3];
        ssq = a + b;
      }
      float S  = sum_xor32(sum_xor16(ssq[0]));
      float Sq = sum_xor32(sum_xor16(ssq[1]));
      const float mu  = S * (1.0f/256.0f);
      const float var = fmaf(Sq, 1.0f/256.0f, -mu*mu);
      const float rs  = __builtin_amdgcn_rsqf(var + LN_EPS);
      const float nrsmu = -rs * mu;
      const float rsc   = rs * c1;
      const float csA   = sel ? rsc : rs;

      // ---- MFMA block B: tile1 chains (16 MFMAs) ----
      __builtin_amdgcn_s_setprio(1);
      #pragma unroll
      for (int kt = 0; kt < 8; ++kt) {
        d11 = __builtin_amdgcn_mfma_f32_16x16x32_f16(Whi[1][kt], bfr[kt], d11, 0, 0, 0);
        d21 = __builtin_amdgcn_mfma_f32_16x16x32_f16(Wlo[1][kt], bfr[kt], d21, 0, 0, 0);
      }
      __builtin_amdgcn_s_setprio(0);

      // ---- tail (packed pairs: a = elems 0,1 ; b = elems 2,3) ----
      float2v pAa, pAb, pBa, pBb, qAa, qAb, qBa, qBb;
      pAa[0] = sel ? d10[0] : d11[0];  pAa[1] = sel ? d10[1] : d11[1];
      pAb[0] = sel ? d10[2] : d11[2];  pAb[1] = sel ? d10[3] : d11[3];
      pBa[0] = sel ? 0.0f   : d21[0];  pBa[1] = sel ? 0.0f   : d21[1];
      pBb[0] = sel ? 0.0f   : d21[2];  pBb[1] = sel ? 0.0f   : d21[3];
      qAa[0] = sel ? d11[0] : d10[0];  qAa[1] = sel ? d11[1] : d10[1];
      qAb[0] = sel ? d11[2] : d10[2];  qAb[1] = sel ? d11[3] : d10[3];
      qBa[0] = sel ? 0.0f   : d20[0];  qBa[1] = sel ? 0.0f   : d20[1];
      qBb[0] = sel ? 0.0f   : d20[2];  qBb[1] = sel ? 0.0f   : d20[3];

      // send/local combines -> v_pk_fma_f32 (values identical to R8b's fmaf)
      const float2v snda = csA*pAa + rsc*pBa;
      const float2v sndb = csA*pAb + rsc*pBb;
      const float2v loca = csA*qAa + rsc*qBa;
      const float2v locb = csA*qAb + rsc*qBb;

      float2v rcva, rcvb;
      rcva[0] = dpp_ror8(snda[0]); rcva[1] = dpp_ror8(snda[1]);
      rcvb[0] = dpp_ror8(sndb[0]); rcvb[1] = dpp_ror8(sndb[1]);

      // base and pre as packed pairs
      float2v gbv_a, gbv_b;
      gbv_a[0] = gbv[0]; gbv_a[1] = gbv[1]; gbv_b[0] = gbv[2]; gbv_b[1] = gbv[3];
      const float2v base_a = nrsmu*wgr_a + gbv_a;   // pk_fma
      const float2v base_b = nrsmu*wgr_b + gbv_b;
      const float2v pre_a  = (loca + rcva) + base_a;
      const float2v pre_b  = (locb + rcvb) + base_b;

      const float t0 = tanh_fast(pre_a[0]);
      const float t1 = tanh_fast(pre_a[1]);
      const float t2 = tanh_fast(pre_b[0]);
      const float t3 = tanh_fast(pre_b[1]);
      th4[0] = t0; th4[1] = t1; th4[2] = t2; th4[3] = t3;
      float s  = ((t0 + t1) + t2) + t3;
      float sq = fmaf(t3, t3, fmaf(t2, t2, fmaf(t1, t1, t0*t0)));

      // g = th * gamma (packed), then packed f32->f16 + residual limb
      float2v g_a, g_b, th_a, th_b;
      th_a[0] = t0; th_a[1] = t1; th_b[0] = t2; th_b[1] = t3;
      g_a = th_a * gmr_a;  g_b = th_b * gmr_b;
      const fp16x2 h01 = __builtin_amdgcn_cvt_pkrtz(g_a[0], g_a[1]);
      const fp16x2 h23 = __builtin_amdgcn_cvt_pkrtz(g_b[0], g_b[1]);
      float2v hf_a, hf_b;
      hf_a[0] = (float)h01[0]; hf_a[1] = (float)h01[1];
      hf_b[0] = (float)h23[0]; hf_b[1] = (float)h23[1];
      const float2v res_a = (g_a - hf_a) * 2048.0f;   // pk_add + pk_mul
      const float2v res_b = (g_b - hf_b) * 2048.0f;
      const fp16x2 l01 = __builtin_amdgcn_cvt_pkrtz(res_a[0], res_a[1]);
      const fp16x2 l23 = __builtin_amdgcn_cvt_pkrtz(res_b[0], res_b[1]);
      half4v hi4, lo4;
      hi4[0] = (_Float16)h01[0]; hi4[1] = (_Float16)h01[1];
      hi4[2] = (_Float16)h23[0]; hi4[3] = (_Float16)h23[1];
      lo4[0] = (_Float16)l01[0]; lo4[1] = (_Float16)l01[1];
      lo4[2] = (_Float16)l23[0]; lo4[3] = (_Float16)l23[1];

      // full in-wave reduction: xor8 (DPP) + xor16 + xor32
      s  += dpp_ror8(s);  s  = sum_xor32(sum_xor16(s));
      sq += dpp_ror8(sq); sq = sum_xor32(sum_xor16(sq));

      _Float16* wp = &sm.Bp[wb][woff];
      *reinterpret_cast<half4v*>(wp)      = hi4;
      *reinterpret_cast<half4v*>(wp + 64) = lo4;
      if (l < 8) {
        float2v v2; v2[0] = s; v2[1] = sq;
        *reinterpret_cast<float2v*>(&sm.red[wb][l][wv*2]) = v2;
      }
      __syncthreads();                           // the ONLY barrier per step
    }
    xQ = xQn;
  }

  // ---- epilogue: final LN (stats in red[0]), h_final in gb space, out GEMM ----
  float mu, rs;
  {
    const float4v pq = *reinterpret_cast<const float4v*>(&sm.red[0][r][q*4]);
    float S  = pq[0] + pq[2];
    float Sq = pq[1] + pq[3];
    S  = sum_xor32(sum_xor16(S));
    Sq = sum_xor32(sum_xor16(Sq));
    mu = S * (1.0f/256.0f);
    const float var = fmaf(Sq, 1.0f/256.0f, -mu*mu);
    rs = __builtin_amdgcn_rsqf(var + LN_EPS);
  }
  float* hf = reinterpret_cast<float*>(&sm.gb[0][0]);   // gb dead after loop
  {
    const float4v btv = *reinterpret_cast<const float4v*>(&bta[n_sel]);
    float4v h4;
    #pragma unroll
    for (int e = 0; e < 4; ++e)
      h4[e] = fmaf((th4[e] - mu) * rs, gmr[e], btv[e]);
    *reinterpret_cast<float4v*>(&hf[r*260 + n_sel]) = h4;
  }
  __syncthreads();
  if (tid < ROWS*10) {
    const int rr = tid / 10, o = tid % 10;
    float acc = bo[o];
    #pragma unroll 4
    for (int n = 0; n < HDIM; ++n)
      acc = fmaf(hf[rr*260 + n], Wo[n*10 + o], acc);
    out[(size_t)(r0 + rr)*10 + o] = acc;
  }
}

extern "C" void kernel_launch(void* const* d_in, const int* in_sizes, int n_in,
                              void* d_out, int out_size, void* d_ws, size_t ws_size,
                              hipStream_t stream) {
  const float* x  = (const float*)d_in[0];
  const float* we = (const float*)d_in[1];
  const float* be = (const float*)d_in[2];
  const float* Wu = (const float*)d_in[3];
  const float* bu = (const float*)d_in[4];
  const float* ga = (const float*)d_in[5];
  const float* bt = (const float*)d_in[6];
  const float* Wo = (const float*)d_in[7];
  const float* bo = (const float*)d_in[8];
  const int B = in_sizes[0] / T_STEPS;          // 2048
  dim3 grid(B / ROWS), block(512);
  rnn_scan_kernel<<<grid, block, 0, stream>>>(x, we, be, Wu, bu, ga, bt, Wo, bo,
                                              (float*)d_out);
}

// Round 15
// 565.969 us; speedup vs baseline: 1.0992x; 1.0992x over previous
//
#include <hip/hip_runtime.h>
#include <hip/hip_fp16.h>
#include <cstdint>

#define T_STEPS 512
#define HDIM    256
#define ROWS    8
#define LN_EPS  1e-5f

typedef _Float16 half8   __attribute__((ext_vector_type(8)));
typedef _Float16 half4v  __attribute__((ext_vector_type(4)));
typedef __fp16   fp16x2  __attribute__((ext_vector_type(2)));   // cvt_pkrtz ret type
typedef float    float4v __attribute__((ext_vector_type(4)));
typedef float    float2v __attribute__((ext_vector_type(2)));
typedef int      int4v   __attribute__((ext_vector_type(4)));
typedef int      int2v   __attribute__((ext_vector_type(2)));

// R11 = exact revert to R8b (573us, session best). R9 (tail-split, 590) and
// R10 (packed VOP3P tail, 622) both regressed: R8b's scalar tail was already
// optimally scheduler-interleaved; restructuring broke the overlap. Budget:
// MFMA 1128 + pure-VALU ~510 + wait ~1050 cyc/step; the wait term is lockstep
// sync, and HIP-level levers (setprio anti-phase = this kernel's +5.6%,
// block-split, tail-split, packing) are measured-exhausted beyond it.
#if __has_builtin(__builtin_amdgcn_permlane32_swap)
#define HAS_PL32 1
#else
#define HAS_PL32 0
#endif
#if __has_builtin(__builtin_amdgcn_permlane16_swap)
#define HAS_PL16 1
#else
#define HAS_PL16 0
#endif

struct __align__(16) Smem {
  _Float16 Bp[2][4096];     // 16384 B packed B fragments (double-buffered)
  float    gb[10][268];     // 10720 B gb[v][n] = tanh(v*we+be)@W + bu + beta@W
  float    wg[260];         // 1040 B  gamma @ W (deferred-LN mu term)
  float    wb[260];         // 1040 B  beta @ W
  float    red[2][8][20];   // 1280 B  [buf][row][wv*2+{0:S,1:Sq}], 8 slots
  int      xi[8][516];      // 16512 B clamped x indices (+4 pad for quad reads)
};

__device__ __forceinline__ float tanh_fast(float x) {
  float e = __expf(2.0f * x);
  float r = __builtin_amdgcn_rcpf(e + 1.0f);
  return fmaf(-2.0f, r, 1.0f);
}
// lane l -> l^8 (rotate-by-8 within each 16-lane row == xor 8), pure VALU
__device__ __forceinline__ float dpp_ror8(float v) {
  return __int_as_float(__builtin_amdgcn_mov_dpp(__float_as_int(v), 0x128, 0xf, 0xf, true));
}
// lane l -> l^16 (within 32-lane half), LDS crossbar, conflict-free (verified R1/R4)
__device__ __forceinline__ float swz_xor16(float v) {
  return __int_as_float(__builtin_amdgcn_ds_swizzle(__float_as_int(v), 0x401F));
}
// v[l] + v[l^16] in every lane
__device__ __forceinline__ float sum_xor16(float v) {
#if HAS_PL16
  int2v r2 = __builtin_amdgcn_permlane16_swap(__float_as_int(v), __float_as_int(v), false, false);
  return __int_as_float(r2[0]) + __int_as_float(r2[1]);
#else
  return v + swz_xor16(v);
#endif
}
// v[l] + v[l^32] in every lane
__device__ __forceinline__ float sum_xor32(float v) {
#if HAS_PL32
  int2v r2 = __builtin_amdgcn_permlane32_swap(__float_as_int(v), __float_as_int(v), false, false);
  return __int_as_float(r2[0]) + __int_as_float(r2[1]);
#else
  return v + __shfl_xor(v, 32, 64);
#endif
}

__global__ __launch_bounds__(512, 1)
void rnn_scan_kernel(const float* __restrict__ x,
                     const float* __restrict__ we,  const float* __restrict__ be,
                     const float* __restrict__ Wu,  const float* __restrict__ bu,
                     const float* __restrict__ gma, const float* __restrict__ bta,
                     const float* __restrict__ Wo,  const float* __restrict__ bo,
                     float* __restrict__ out)
{
  __shared__ Smem sm;
  const int tid = threadIdx.x;
  const int wv  = tid >> 6;        // wave 0..7, owns n in [32*wv, 32*wv+32)
  const int l   = tid & 63;
  const int q   = l >> 4;
  const int m   = l & 15;
  const int sel = m >> 3;          // 0: finalize nt=0 (hi cols), 1: nt=1
  const int r   = m & 7;           // batch row within tile
  const int r0  = blockIdx.x * ROWS;

  // ---- init 0: x -> clamped int indices in LDS (the ONLY x reads) ----
  for (int i = tid; i < ROWS * T_STEPS; i += 512) {
    const int rr = i >> 9, c = i & (T_STEPS - 1);
    int xv = (int)x[(size_t)(r0 + rr) * T_STEPS + c];
    xv = xv < 0 ? 0 : (xv > 9 ? 9 : xv);
    sm.xi[rr][c] = xv;
  }
  if (tid < ROWS) {                // 4-entry zero pad for the quad prefetch
    sm.xi[tid][512] = 0; sm.xi[tid][513] = 0;
    sm.xi[tid][514] = 0; sm.xi[tid][515] = 0;
  }

  // ---- init 1: embed-tanh table in (to-be-zeroed) Bp space ----
  float* et = reinterpret_cast<float*>(&sm.Bp[0][0]);   // 10240 B < 16384 B
  if (tid < HDIM) {
    const float wek = we[tid], bek = be[tid];
    #pragma unroll
    for (int v = 0; v < 10; ++v)
      et[v*HDIM + tid] = tanh_fast(fmaf((float)v, wek, bek));
  }
  __syncthreads();

  // ---- init 2: gb = et@W + bu ; wg = gamma@W ; wb = beta@W ----
  {
    const int g = tid >> 8;        // 0: v=0..4 + wg, 1: v=5..9 + wb
    const int n = tid & 255;
    float acc[5] = {0,0,0,0,0};
    float accx = 0.0f;
    const int vb = g * 5;
    for (int k = 0; k < HDIM; ++k) {
      const float wk = Wu[(size_t)k*HDIM + n];
      #pragma unroll
      for (int v = 0; v < 5; ++v) acc[v] = fmaf(et[(vb+v)*HDIM + k], wk, acc[v]);
      const float xk = g ? bta[k] : gma[k];
      accx = fmaf(xk, wk, accx);
    }
    const float bun = bu[n];
    #pragma unroll
    for (int v = 0; v < 5; ++v) sm.gb[vb+v][n] = acc[v] + bun;
    if (g == 0) sm.wg[n] = accx; else sm.wb[n] = accx;
  }
  __syncthreads();

  // ---- init 3: fold beta@W into gb; zero Bp (both bufs) and red ----
  if (tid < HDIM) {
    const float wbn = sm.wb[tid];
    #pragma unroll
    for (int v = 0; v < 10; ++v) sm.gb[v][tid] += wbn;
  }
  {
    uint32_t* p = reinterpret_cast<uint32_t*>(&sm.Bp[0][0]);
    for (int i = tid; i < 4096; i += 512) p[i] = 0u;      // 16 KB = both bufs
  }
  if (tid < 320) (&sm.red[0][0][0])[tid] = 0.0f;

  // ---- persistent W fragments: full K, this wave's two 16-wide n-tiles ----
  half8 Whi[2][8], Wlo[2][8];
  #pragma unroll
  for (int nt = 0; nt < 2; ++nt) {
    const int n = wv*32 + nt*16 + m;
    #pragma unroll
    for (int kt = 0; kt < 8; ++kt) {
      const int k0 = kt*32 + q*8;
      half8 hi, lo;
      #pragma unroll
      for (int j = 0; j < 8; ++j) {
        float v = Wu[(size_t)(k0 + j)*HDIM + n];           // L2-hot across blocks
        _Float16 h = (_Float16)v;
        hi[j] = h;
        lo[j] = (_Float16)((v - (float)h) * 2048.0f);
      }
      Whi[nt][kt] = hi; Wlo[nt][kt] = lo;
    }
  }
  const int n_sel = wv*32 + sel*16 + q*4;    // this lane's 4 finalized columns
  const float4v gmr = *reinterpret_cast<const float4v*>(&gma[n_sel]);
  __syncthreads();                            // wg/gb/xi ready, buffers zeroed
  const float4v wgr = *reinterpret_cast<const float4v*>(&sm.wg[n_sel]);

  const float c1 = 4.8828125e-4f;             // 2^-11
  const float* gbp = &sm.gb[0][n_sel];
  float4v th4;                                // last tanh outputs (epilogue)

  // per-lane constant LDS offsets (halves)
  const int rdoff = l * 8;                                        // B read base
  const int woff  = wv*512 + (2*sel + (q>>1))*128 + r*8 + (q&1)*4; // hi write; lo at +64

  // x-index quad prefetch (one b128 per 4 steps) + gb bias row one step ahead
  int4v xQ = *reinterpret_cast<const int4v*>(&sm.xi[r][0]);
  float4v gbv_n = *reinterpret_cast<const float4v*>(gbp + xQ[0]*268);

  for (int k = 0; k < T_STEPS/4; ++k) {
    const int4v xQn = *reinterpret_cast<const int4v*>(&sm.xi[r][k*4 + 4]);
    #pragma unroll
    for (int e = 0; e < 4; ++e) {
      const int rb = e & 1, wb = rb ^ 1;

      // issue red chunk read NOW, consume in the stats block (latency hidden)
      const float4v pq = *reinterpret_cast<const float4v*>(&sm.red[rb][r][q*4]);

      const float4v gbv = gbv_n;                 // bias row for THIS step
      const int xv2 = (e < 3) ? xQ[e + 1] : xQn[0];   // compile-time select

      // hoist all B fragments into registers (static-indexed; rule #20 safe)
      const _Float16* pbB = &sm.Bp[rb][rdoff];
      half8 bfr[8];
      #pragma unroll
      for (int kt = 0; kt < 8; ++kt)
        bfr[kt] = *reinterpret_cast<const half8*>(pbB + kt*512);

      // ---- MFMA block A: tile0 chains (16 MFMAs) ----
      float4v d10, d11, d20, d21;
      d10 = 0.0f; d11 = 0.0f; d20 = 0.0f; d21 = 0.0f;
      __builtin_amdgcn_s_setprio(1);
      #pragma unroll
      for (int kt = 0; kt < 8; ++kt) {
        d10 = __builtin_amdgcn_mfma_f32_16x16x32_f16(Whi[0][kt], bfr[kt], d10, 0, 0, 0);
        d20 = __builtin_amdgcn_mfma_f32_16x16x32_f16(Wlo[0][kt], bfr[kt], d20, 0, 0, 0);
      }
      __builtin_amdgcn_s_setprio(0);

      // ---- stats block (independent VALU, anti-phases vs partner's MFMAs) ----
      gbv_n = *reinterpret_cast<const float4v*>(gbp + xv2*268);   // t+1 prefetch
      float S  = pq[0] + pq[2];
      float Sq = pq[1] + pq[3];
      S  = sum_xor32(sum_xor16(S));
      Sq = sum_xor32(sum_xor16(Sq));
      const float mu  = S * (1.0f/256.0f);
      const float var = fmaf(Sq, 1.0f/256.0f, -mu*mu);
      const float rs  = __builtin_amdgcn_rsqf(var + LN_EPS);
      const float nrsmu = -rs * mu;
      const float rsc   = rs * c1;
      const float csA   = sel ? rsc : rs;

      // ---- MFMA block B: tile1 chains (16 MFMAs) ----
      __builtin_amdgcn_s_setprio(1);
      #pragma unroll
      for (int kt = 0; kt < 8; ++kt) {
        d11 = __builtin_amdgcn_mfma_f32_16x16x32_f16(Whi[1][kt], bfr[kt], d11, 0, 0, 0);
        d21 = __builtin_amdgcn_mfma_f32_16x16x32_f16(Wlo[1][kt], bfr[kt], d21, 0, 0, 0);
      }
      __builtin_amdgcn_s_setprio(0);

      // ---- tail: reassemble 3 products per output from its two B columns ----
      float4v sendv, locv;
      #pragma unroll
      for (int i2 = 0; i2 < 4; ++i2) {
        const float pA = sel ? d10[i2] : d11[i2];
        const float pB = sel ? 0.0f    : d21[i2];
        sendv[i2] = fmaf(csA, pA, rsc * pB);
        const float qA = sel ? d11[i2] : d10[i2];
        const float qB = sel ? 0.0f    : d20[i2];
        locv[i2]  = fmaf(csA, qA, rsc * qB);
      }
      float4v recv;
      #pragma unroll
      for (int i2 = 0; i2 < 4; ++i2) recv[i2] = dpp_ror8(sendv[i2]);

      float s = 0.0f, sq = 0.0f;
      float g2v[4];
      #pragma unroll
      for (int i2 = 0; i2 < 4; ++i2) {
        const float base = fmaf(nrsmu, wgr[i2], gbv[i2]);
        const float pre  = locv[i2] + recv[i2] + base;
        const float th   = tanh_fast(pre);
        th4[i2] = th; s += th; sq = fmaf(th, th, sq);
        g2v[i2] = th * gmr[i2];
      }
      // packed f32->f16 (rtz safe: lo limb self-corrects hi rounding)
      const fp16x2 h01 = __builtin_amdgcn_cvt_pkrtz(g2v[0], g2v[1]);
      const fp16x2 h23 = __builtin_amdgcn_cvt_pkrtz(g2v[2], g2v[3]);
      const float r0f = (g2v[0] - (float)h01[0]) * 2048.0f;
      const float r1f = (g2v[1] - (float)h01[1]) * 2048.0f;
      const float r2f = (g2v[2] - (float)h23[0]) * 2048.0f;
      const float r3f = (g2v[3] - (float)h23[1]) * 2048.0f;
      const fp16x2 l01 = __builtin_amdgcn_cvt_pkrtz(r0f, r1f);
      const fp16x2 l23 = __builtin_amdgcn_cvt_pkrtz(r2f, r3f);
      half4v hi4, lo4;
      hi4[0] = (_Float16)h01[0]; hi4[1] = (_Float16)h01[1];
      hi4[2] = (_Float16)h23[0]; hi4[3] = (_Float16)h23[1];
      lo4[0] = (_Float16)l01[0]; lo4[1] = (_Float16)l01[1];
      lo4[2] = (_Float16)l23[0]; lo4[3] = (_Float16)l23[1];

      // full in-wave reduction: xor8 (DPP) + xor16 + xor32
      s  += dpp_ror8(s);  s  = sum_xor32(sum_xor16(s));
      sq += dpp_ror8(sq); sq = sum_xor32(sum_xor16(sq));

      _Float16* wp = &sm.Bp[wb][woff];
      *reinterpret_cast<half4v*>(wp)      = hi4;
      *reinterpret_cast<half4v*>(wp + 64) = lo4;
      if (l < 8) {
        float2v v2; v2[0] = s; v2[1] = sq;
        *reinterpret_cast<float2v*>(&sm.red[wb][l][wv*2]) = v2;
      }
      __syncthreads();                           // the ONLY barrier per step
    }
    xQ = xQn;
  }

  // ---- epilogue: final LN (stats in red[0]), h_final in gb space, out GEMM ----
  float mu, rs;
  {
    const float4v pq = *reinterpret_cast<const float4v*>(&sm.red[0][r][q*4]);
    float S  = pq[0] + pq[2];
    float Sq = pq[1] + pq[3];
    S  = sum_xor32(sum_xor16(S));
    Sq = sum_xor32(sum_xor16(Sq));
    mu = S * (1.0f/256.0f);
    const float var = fmaf(Sq, 1.0f/256.0f, -mu*mu);
    rs = __builtin_amdgcn_rsqf(var + LN_EPS);
  }
  float* hf = reinterpret_cast<float*>(&sm.gb[0][0]);   // gb dead after loop
  {
    const float4v btv = *reinterpret_cast<const float4v*>(&bta[n_sel]);
    float4v h4;
    #pragma unroll
    for (int e = 0; e < 4; ++e)
      h4[e] = fmaf((th4[e] - mu) * rs, gmr[e], btv[e]);
    *reinterpret_cast<float4v*>(&hf[r*260 + n_sel]) = h4;
  }
  __syncthreads();
  if (tid < ROWS*10) {
    const int rr = tid / 10, o = tid % 10;
    float acc = bo[o];
    #pragma unroll 4
    for (int n = 0; n < HDIM; ++n)
      acc = fmaf(hf[rr*260 + n], Wo[n*10 + o], acc);
    out[(size_t)(r0 + rr)*10 + o] = acc;
  }
}

extern "C" void kernel_launch(void* const* d_in, const int* in_sizes, int n_in,
                              void* d_out, int out_size, void* d_ws, size_t ws_size,
                              hipStream_t stream) {
  const float* x  = (const float*)d_in[0];
  const float* we = (const float*)d_in[1];
  const float* be = (const float*)d_in[2];
  const float* Wu = (const float*)d_in[3];
  const float* bu = (const float*)d_in[4];
  const float* ga = (const float*)d_in[5];
  const float* bt = (const float*)d_in[6];
  const float* Wo = (const float*)d_in[7];
  const float* bo = (const float*)d_in[8];
  const int B = in_sizes[0] / T_STEPS;          // 2048
  dim3 grid(B / ROWS), block(512);
  rnn_scan_kernel<<<grid, block, 0, stream>>>(x, we, be, Wu, bu, ga, bt, Wo, bo,
                                              (float*)d_out);
}